// Round 2
// baseline (272.760 us; speedup 1.0000x reference)
//
#include <hip/hip_runtime.h>

#define D 512
#define NROWS 8192
#define MROWS 8192
#define NCHUNK 16
#define CHUNK_COLS (MROWS / NCHUNK)   // 512
#define SUBTILES (CHUNK_COLS / 128)   // 4
#define LOG2E 1.4426950408889634f
#define LN2 0.6931471805599453f

typedef float floatx4 __attribute__((ext_vector_type(4)));
typedef __bf16 bf16x8 __attribute__((ext_vector_type(8)));
typedef unsigned short ushortx4 __attribute__((ext_vector_type(4)));

typedef __attribute__((address_space(1))) void* as1_void_p;
typedef __attribute__((address_space(3))) void* as3_void_p;

__device__ __forceinline__ void async_cp16(const void* g, void* l) {
    __builtin_amdgcn_global_load_lds((as1_void_p)(void*)g, (as3_void_p)l, 16, 0, 0);
}

__device__ __forceinline__ unsigned short f2bf(float f) {
    unsigned u = __float_as_uint(f);
    u += 0x7fffu + ((u >> 16) & 1u);
    return (unsigned short)(u >> 16);
}
__device__ __forceinline__ float bf2f(unsigned short h) {
    return __uint_as_float(((unsigned)h) << 16);
}

// fast tanh: clamp then (e-1)/(e+1), e = 2^(2x*log2e). |err| ~1e-7 rel, fine for bf16.
__device__ __forceinline__ float fast_tanh(float x) {
    const float xc = fminf(fmaxf(x, -15.0f), 15.0f);
    const float e = __builtin_exp2f(xc * (2.0f * LOG2E));
    return (e - 1.0f) * __builtin_amdgcn_rcpf(e + 1.0f);
}

// ---------------------------------------------------------------------------
// Kernel 1: x -> bf16(x * log2e) + row ||x||^2 (fp32). Also zeroes d_out.
__global__ void k_prep_x(const float* __restrict__ x,
                         unsigned short* __restrict__ xb,
                         float* __restrict__ xsq,
                         float* __restrict__ out) {
    const int row = blockIdx.x;
    const int t = threadIdx.x;  // 256
    if (row == 0 && t == 0) out[0] = 0.f;
    const float2 v = ((const float2*)(x + (size_t)row * D))[t];
    const unsigned short b0 = f2bf(v.x * LOG2E), b1 = f2bf(v.y * LOG2E);
    ((unsigned*)(xb + (size_t)row * D))[t] = (unsigned)b0 | ((unsigned)b1 << 16);
    float s = v.x * v.x + v.y * v.y;
    #pragma unroll
    for (int m = 1; m < 64; m <<= 1) s += __shfl_xor(s, m);
    __shared__ float ws4[4];
    if ((t & 63) == 0) ws4[t >> 6] = s;
    __syncthreads();
    if (t == 0) xsq[row] = ws4[0] + ws4[1] + ws4[2] + ws4[3];
}

// ---------------------------------------------------------------------------
// Kernel 2: fp32 -> bf16, 4/thread (used for mu).
__global__ void k_convert(const float* __restrict__ src,
                          unsigned short* __restrict__ dst, int n4) {
    const int i = blockIdx.x * blockDim.x + threadIdx.x;
    if (i < n4) {
        const float4 v = ((const float4*)src)[i];
        ushortx4 o;
        o.x = f2bf(v.x); o.y = f2bf(v.y); o.z = f2bf(v.z); o.w = f2bf(v.w);
        ((ushortx4*)dst)[i] = o;
    }
}

// Kernel 2b: convert W AND zero fsq (fsq is accumulated by k_fgemm atomics).
__global__ void k_convert_w(const float* __restrict__ src,
                            unsigned short* __restrict__ dst, int n4,
                            float* __restrict__ fsq) {
    const int i = blockIdx.x * blockDim.x + threadIdx.x;
    if (i < n4) {
        const float4 v = ((const float4*)src)[i];
        ushortx4 o;
        o.x = f2bf(v.x); o.y = f2bf(v.y); o.z = f2bf(v.z); o.w = f2bf(v.w);
        ((ushortx4*)dst)[i] = o;
    }
    if (i < MROWS) fsq[i] = 0.f;
}

// ---------------------------------------------------------------------------
// Kernel 3: f = tanh(mu @ W^T + b) -> bf16; fused row sum-of-squares via
// per-block partial + atomicAdd. XOR-swizzled LDS (bank-conflict-free frags).
__global__ __launch_bounds__(256, 2)
void k_fgemm(const unsigned short* __restrict__ mub,
             const unsigned short* __restrict__ Wb,
             const float* __restrict__ bias,
             unsigned short* __restrict__ fb,
             float* __restrict__ fsq) {
    __shared__ unsigned short Ab[128 * 32];
    __shared__ unsigned short Bb[128 * 32];

    const int tid = threadIdx.x;
    const int wave = tid >> 6;
    const int lane = tid & 63;
    const int wr = wave >> 1, wc = wave & 1;
    const int g = lane >> 4;
    const int lm = lane & 15;

    const int row0 = blockIdx.x * 128;
    const int col0 = blockIdx.y * 128;

    // staging: thread tid owns LDS granule tid (16B). Source granule is
    // XOR-swizzled so fragment reads are bank-conflict-free.
    const int srow = tid >> 2;
    const int gsrc = (tid & 3) ^ ((srow >> 1) & 3);
    const unsigned short* gA = mub + (size_t)(row0 + srow) * D + gsrc * 8;
    const unsigned short* gB = Wb  + (size_t)(col0 + srow) * D + gsrc * 8;
    char* lA = ((char*)Ab) + wave * 1024;
    char* lB = ((char*)Bb) + wave * 1024;

    const int xsel = (lm >> 1) & 3;
    const unsigned short* fragA = Ab + (64 * wr + lm) * 32 + (g ^ xsel) * 8;
    const unsigned short* fragB = Bb + (64 * wc + lm) * 32 + (g ^ xsel) * 8;

    floatx4 acc[4][4];
    const floatx4 zz = {0.f, 0.f, 0.f, 0.f};
    #pragma unroll
    for (int i = 0; i < 4; ++i)
        #pragma unroll
        for (int j = 0; j < 4; ++j) acc[i][j] = zz;

    for (int kt = 0; kt < 16; ++kt) {
        const int k0 = kt * 32;
        async_cp16(gA + k0, lA);
        async_cp16(gA + 64 * D + k0, lA + 4096);
        async_cp16(gB + k0, lB);
        async_cp16(gB + 64 * D + k0, lB + 4096);
        __syncthreads();
        bf16x8 af[4], bfr[4];
        #pragma unroll
        for (int i = 0; i < 4; ++i) af[i] = *(const bf16x8*)(fragA + i * 512);
        #pragma unroll
        for (int j = 0; j < 4; ++j) bfr[j] = *(const bf16x8*)(fragB + j * 512);
        #pragma unroll
        for (int i = 0; i < 4; ++i)
            #pragma unroll
            for (int j = 0; j < 4; ++j)
                acc[i][j] = __builtin_amdgcn_mfma_f32_16x16x32_bf16(af[i], bfr[j], acc[i][j], 0, 0, 0);
        __syncthreads();
    }

    float bcol[4];
    #pragma unroll
    for (int j = 0; j < 4; ++j) bcol[j] = bias[col0 + 64 * wc + 16 * j + lm];
    #pragma unroll
    for (int i = 0; i < 4; ++i) {
        #pragma unroll
        for (int r = 0; r < 4; ++r) {
            const int row = row0 + 64 * wr + 16 * i + 4 * g + r;
            float sq = 0.f;
            #pragma unroll
            for (int j = 0; j < 4; ++j) {
                const int col = col0 + 64 * wc + 16 * j + lm;
                const unsigned short h = f2bf(fast_tanh(acc[i][j][r] + bcol[j]));
                fb[(size_t)row * D + col] = h;
                const float fr = bf2f(h);
                sq += fr * fr;
            }
            // reduce sq across the 16-lane group (same row, different cols)
            #pragma unroll
            for (int d = 1; d < 16; d <<= 1) sq += __shfl_xor(sq, d);
            if (lm == 0) atomicAdd(fsq + row, sq);
        }
    }
}

// ---------------------------------------------------------------------------
// Kernel 4: fused cross-GEMM + per-lane online logsumexp (log2 domain).
// acc = log2e * (x . f) because xb is pre-scaled. Scores s' = acc - 0.5*log2e*fsq.
// Each block: 128 rows x one 512-col chunk (4 subtiles). Grid 64 x 16.
__global__ __launch_bounds__(256, 3)
void k_cross(const unsigned short* __restrict__ xb,
             const unsigned short* __restrict__ fb,
             const float* __restrict__ fsq,
             float* __restrict__ pmax,
             float* __restrict__ psum) {
    __shared__ unsigned short Ab[128 * 32];
    __shared__ unsigned short Bb[128 * 32];
    __shared__ float mbuf[128], sbuf[128];

    const int tid = threadIdx.x;
    const int wave = tid >> 6;
    const int lane = tid & 63;
    const int wr = wave >> 1, wc = wave & 1;
    const int g = lane >> 4;
    const int lm = lane & 15;

    const int row0 = blockIdx.x * 128;
    const int chunk = blockIdx.y;

    const int srow = tid >> 2;
    const int gsrc = (tid & 3) ^ ((srow >> 1) & 3);
    const unsigned short* gA = xb + (size_t)(row0 + srow) * D + gsrc * 8;
    char* lA = ((char*)Ab) + wave * 1024;
    char* lB = ((char*)Bb) + wave * 1024;

    const int xsel = (lm >> 1) & 3;
    const unsigned short* fragA = Ab + (64 * wr + lm) * 32 + (g ^ xsel) * 8;
    const unsigned short* fragB = Bb + (64 * wc + lm) * 32 + (g ^ xsel) * 8;

    // per-lane online softmax state: 16 row-slots (i, r), local cols only
    float m_loc[4][4], s_loc[4][4];
    #pragma unroll
    for (int i = 0; i < 4; ++i)
        #pragma unroll
        for (int r = 0; r < 4; ++r) { m_loc[i][r] = -__builtin_inff(); s_loc[i][r] = 0.f; }

    for (int st = 0; st < SUBTILES; ++st) {
        const int col0 = chunk * CHUNK_COLS + st * 128;
        const unsigned short* gB = fb + (size_t)(col0 + srow) * D + gsrc * 8;

        floatx4 acc[4][4];
        const floatx4 zz = {0.f, 0.f, 0.f, 0.f};
        #pragma unroll
        for (int i = 0; i < 4; ++i)
            #pragma unroll
            for (int j = 0; j < 4; ++j) acc[i][j] = zz;

        for (int kt = 0; kt < 16; ++kt) {
            const int k0 = kt * 32;
            async_cp16(gA + k0, lA);
            async_cp16(gA + 64 * D + k0, lA + 4096);
            async_cp16(gB + k0, lB);
            async_cp16(gB + 64 * D + k0, lB + 4096);
            __syncthreads();
            bf16x8 af[4], bfr[4];
            #pragma unroll
            for (int i = 0; i < 4; ++i) af[i] = *(const bf16x8*)(fragA + i * 512);
            #pragma unroll
            for (int j = 0; j < 4; ++j) bfr[j] = *(const bf16x8*)(fragB + j * 512);
            #pragma unroll
            for (int i = 0; i < 4; ++i)
                #pragma unroll
                for (int j = 0; j < 4; ++j)
                    acc[i][j] = __builtin_amdgcn_mfma_f32_16x16x32_bf16(af[i], bfr[j], acc[i][j], 0, 0, 0);
            __syncthreads();
        }

        // per-lane online update, no barriers, no shuffles
        float hf[4];
        #pragma unroll
        for (int j = 0; j < 4; ++j)
            hf[j] = 0.5f * LOG2E * fsq[col0 + 64 * wc + 16 * j + lm];
        #pragma unroll
        for (int i = 0; i < 4; ++i) {
            #pragma unroll
            for (int r = 0; r < 4; ++r) {
                float v0 = acc[i][0][r] - hf[0];
                float v1 = acc[i][1][r] - hf[1];
                float v2 = acc[i][2][r] - hf[2];
                float v3 = acc[i][3][r] - hf[3];
                const float mm = fmaxf(fmaxf(v0, v1), fmaxf(v2, v3));
                const float nm = fmaxf(m_loc[i][r], mm);
                s_loc[i][r] = s_loc[i][r] * __builtin_exp2f(m_loc[i][r] - nm)
                            + __builtin_exp2f(v0 - nm) + __builtin_exp2f(v1 - nm)
                            + __builtin_exp2f(v2 - nm) + __builtin_exp2f(v3 - nm);
                m_loc[i][r] = nm;
            }
        }
    }

    // merge across the 16-lane group (butterfly on (m,s))
    #pragma unroll
    for (int i = 0; i < 4; ++i) {
        #pragma unroll
        for (int r = 0; r < 4; ++r) {
            float m = m_loc[i][r], s = s_loc[i][r];
            #pragma unroll
            for (int d = 1; d < 16; d <<= 1) {
                const float om = __shfl_xor(m, d);
                const float os = __shfl_xor(s, d);
                const float nm = fmaxf(m, om);
                s = s * __builtin_exp2f(m - nm) + os * __builtin_exp2f(om - nm);
                m = nm;
            }
            m_loc[i][r] = m; s_loc[i][r] = s;
        }
    }
    // merge the two column-waves (wc) via LDS, then write partials
    if (wc == 0 && lm == 0) {
        #pragma unroll
        for (int i = 0; i < 4; ++i)
            #pragma unroll
            for (int r = 0; r < 4; ++r) {
                const int rl = 64 * wr + 16 * i + 4 * g + r;
                mbuf[rl] = m_loc[i][r]; sbuf[rl] = s_loc[i][r];
            }
    }
    __syncthreads();
    if (wc == 1 && lm == 0) {
        #pragma unroll
        for (int i = 0; i < 4; ++i)
            #pragma unroll
            for (int r = 0; r < 4; ++r) {
                const int rl = 64 * wr + 16 * i + 4 * g + r;
                const float om = mbuf[rl], os = sbuf[rl];
                float m = m_loc[i][r], s = s_loc[i][r];
                const float nm = fmaxf(m, om);
                s = s * __builtin_exp2f(m - nm) + os * __builtin_exp2f(om - nm);
                pmax[(size_t)(row0 + rl) * NCHUNK + chunk] = nm;
                psum[(size_t)(row0 + rl) * NCHUNK + chunk] = s;
            }
    }
}

// ---------------------------------------------------------------------------
// Kernel 5: combine partials -> out += -sum lse (32 blocks, one atomic each).
// lse_n = ln2 * (gm + log2(s)) - 0.5 * xsq_n
__global__ void k_finish(const float* __restrict__ pmax,
                         const float* __restrict__ psum,
                         const float* __restrict__ xsq,
                         float* __restrict__ out) {
    const int row = blockIdx.x * 256 + threadIdx.x;
    const float4* pm4 = (const float4*)(pmax + (size_t)row * NCHUNK);
    const float4* ps4 = (const float4*)(psum + (size_t)row * NCHUNK);
    float pm[NCHUNK], ps[NCHUNK];
    #pragma unroll
    for (int c = 0; c < NCHUNK / 4; ++c) {
        const float4 a = pm4[c], b = ps4[c];
        pm[4*c] = a.x; pm[4*c+1] = a.y; pm[4*c+2] = a.z; pm[4*c+3] = a.w;
        ps[4*c] = b.x; ps[4*c+1] = b.y; ps[4*c+2] = b.z; ps[4*c+3] = b.w;
    }
    float gm = -__builtin_inff();
    #pragma unroll
    for (int c = 0; c < NCHUNK; ++c) gm = fmaxf(gm, pm[c]);
    float s = 0.f;
    #pragma unroll
    for (int c = 0; c < NCHUNK; ++c) s += ps[c] * __builtin_exp2f(pm[c] - gm);
    float lse = LN2 * (gm + __builtin_log2f(s)) - 0.5f * xsq[row];
    #pragma unroll
    for (int m = 1; m < 64; m <<= 1) lse += __shfl_xor(lse, m);
    __shared__ float ws4[4];
    if ((threadIdx.x & 63) == 0) ws4[threadIdx.x >> 6] = lse;
    __syncthreads();
    if (threadIdx.x == 0) atomicAdd(out, -(ws4[0] + ws4[1] + ws4[2] + ws4[3]));
}

// ---------------------------------------------------------------------------
extern "C" void kernel_launch(void* const* d_in, const int* in_sizes, int n_in,
                              void* d_out, int out_size, void* d_ws, size_t ws_size,
                              hipStream_t stream) {
    const float* x  = (const float*)d_in[0];   // (8192, 512)
    const float* mu = (const float*)d_in[1];   // (8192, 512)
    const float* W  = (const float*)d_in[2];   // (512, 512)
    const float* b  = (const float*)d_in[3];   // (512,)

    char* ws = (char*)d_ws;
    unsigned short* xb  = (unsigned short*)(ws);                    // 8 MB
    unsigned short* fb  = (unsigned short*)(ws + (8u << 20));       // 8 MB
    unsigned short* mub = (unsigned short*)(ws + (16u << 20));      // 8 MB
    unsigned short* Wb  = (unsigned short*)(ws + (24u << 20));      // 512 KB
    float* xsq  = (float*)(ws + (25u << 20));                       // 32 KB
    float* fsq  = xsq + NROWS;                                      // 32 KB
    float* pmax = fsq + MROWS;                                      // 512 KB
    float* psum = pmax + (size_t)NROWS * NCHUNK;                    // 512 KB

    float* out = (float*)d_out;

    hipLaunchKernelGGL(k_prep_x, dim3(NROWS), dim3(256), 0, stream, x, xb, xsq, out);
    hipLaunchKernelGGL(k_convert, dim3(4096), dim3(256), 0, stream, mu, mub, MROWS * D / 4);
    hipLaunchKernelGGL(k_convert_w, dim3(256), dim3(256), 0, stream, W, Wb, D * D / 4, fsq);
    hipLaunchKernelGGL(k_fgemm, dim3(MROWS / 128, D / 128), dim3(256), 0, stream, mub, Wb, b, fb, fsq);
    hipLaunchKernelGGL(k_cross, dim3(NROWS / 128, NCHUNK), dim3(256), 0, stream,
                       xb, fb, fsq, pmax, psum);
    hipLaunchKernelGGL(k_finish, dim3(NROWS / 256), dim3(256), 0, stream, pmax, psum, xsq, out);
}

// Round 3
// 202.793 us; speedup vs baseline: 1.3450x; 1.3450x over previous
//
#include <hip/hip_runtime.h>

#define D 512
#define NROWS 8192
#define MROWS 8192
#define NCHUNK 8
#define CHUNK_COLS (MROWS / NCHUNK)   // 1024
#define SUBTILES (CHUNK_COLS / 128)   // 8
#define LOG2E 1.4426950408889634f
#define LN2 0.6931471805599453f

typedef float floatx4 __attribute__((ext_vector_type(4)));
typedef __bf16 bf16x8 __attribute__((ext_vector_type(8)));
typedef unsigned short ushortx4 __attribute__((ext_vector_type(4)));

typedef __attribute__((address_space(1))) void* as1_void_p;
typedef __attribute__((address_space(3))) void* as3_void_p;

__device__ __forceinline__ void async_cp16(const void* g, void* l) {
    __builtin_amdgcn_global_load_lds((as1_void_p)(void*)g, (as3_void_p)l, 16, 0, 0);
}

__device__ __forceinline__ unsigned short f2bf(float f) {
    unsigned u = __float_as_uint(f);
    u += 0x7fffu + ((u >> 16) & 1u);
    return (unsigned short)(u >> 16);
}
__device__ __forceinline__ float bf2f(unsigned short h) {
    return __uint_as_float(((unsigned)h) << 16);
}

// fast tanh: clamp then (e-1)/(e+1), e = 2^(2x*log2e).
__device__ __forceinline__ float fast_tanh(float x) {
    const float xc = fminf(fmaxf(x, -15.0f), 15.0f);
    const float e = __builtin_exp2f(xc * (2.0f * LOG2E));
    return (e - 1.0f) * __builtin_amdgcn_rcpf(e + 1.0f);
}

// ---------------------------------------------------------------------------
// Kernel 1 (fused prep): blocks [0,8192): x row -> bf16(x*log2e) + ||x||^2;
// blocks [8192,12288): mu -> bf16; blocks [12288,12544): W -> bf16 + zero fsq.
// Block 0 also zeroes out[0].
#define NB_X NROWS
#define NB_MU (MROWS * D / 1024)      // 4096
#define NB_W (D * D / 1024)           // 256
__global__ void k_prep(const float* __restrict__ x,
                       const float* __restrict__ mu,
                       const float* __restrict__ W,
                       unsigned short* __restrict__ xb,
                       unsigned short* __restrict__ mub,
                       unsigned short* __restrict__ Wb,
                       float* __restrict__ xsq,
                       float* __restrict__ fsq,
                       float* __restrict__ out) {
    const int bid = blockIdx.x;
    const int t = threadIdx.x;  // 256
    if (bid < NB_X) {
        if (bid == 0 && t == 0) out[0] = 0.f;
        const float2 v = ((const float2*)(x + (size_t)bid * D))[t];
        const unsigned short b0 = f2bf(v.x * LOG2E), b1 = f2bf(v.y * LOG2E);
        ((unsigned*)(xb + (size_t)bid * D))[t] = (unsigned)b0 | ((unsigned)b1 << 16);
        float s = v.x * v.x + v.y * v.y;
        #pragma unroll
        for (int m = 1; m < 64; m <<= 1) s += __shfl_xor(s, m);
        __shared__ float ws4[4];
        if ((t & 63) == 0) ws4[t >> 6] = s;
        __syncthreads();
        if (t == 0) xsq[bid] = ws4[0] + ws4[1] + ws4[2] + ws4[3];
    } else if (bid < NB_X + NB_MU) {
        const int i = (bid - NB_X) * 256 + t;
        const float4 v = ((const float4*)mu)[i];
        ushortx4 o;
        o.x = f2bf(v.x); o.y = f2bf(v.y); o.z = f2bf(v.z); o.w = f2bf(v.w);
        ((ushortx4*)mub)[i] = o;
    } else {
        const int wb_blk = bid - NB_X - NB_MU;
        const int i = wb_blk * 256 + t;
        const float4 v = ((const float4*)W)[i];
        ushortx4 o;
        o.x = f2bf(v.x); o.y = f2bf(v.y); o.z = f2bf(v.z); o.w = f2bf(v.w);
        ((ushortx4*)Wb)[i] = o;
        if (t < 32) fsq[wb_blk * 32 + t] = 0.f;
    }
}

// ---------------------------------------------------------------------------
// Kernel 2: f = tanh(mu @ W^T + b) -> bf16; fused row ||f||^2 via atomics.
// XOR-swizzled LDS staging (verified conflict-free in round 2).
__global__ __launch_bounds__(256, 2)
void k_fgemm(const unsigned short* __restrict__ mub,
             const unsigned short* __restrict__ Wb,
             const float* __restrict__ bias,
             unsigned short* __restrict__ fb,
             float* __restrict__ fsq) {
    __shared__ unsigned short Ab[128 * 32];
    __shared__ unsigned short Bb[128 * 32];

    const int tid = threadIdx.x;
    const int wave = tid >> 6;
    const int lane = tid & 63;
    const int wr = wave >> 1, wc = wave & 1;
    const int g = lane >> 4;
    const int lm = lane & 15;

    const int row0 = blockIdx.x * 128;
    const int col0 = blockIdx.y * 128;

    const int srow = tid >> 2;
    const int gsrc = (tid & 3) ^ ((srow >> 1) & 3);
    const unsigned short* gA = mub + (size_t)(row0 + srow) * D + gsrc * 8;
    const unsigned short* gB = Wb  + (size_t)(col0 + srow) * D + gsrc * 8;
    char* lA = ((char*)Ab) + wave * 1024;
    char* lB = ((char*)Bb) + wave * 1024;

    const int xsel = (lm >> 1) & 3;
    const unsigned short* fragA = Ab + (64 * wr + lm) * 32 + (g ^ xsel) * 8;
    const unsigned short* fragB = Bb + (64 * wc + lm) * 32 + (g ^ xsel) * 8;

    floatx4 acc[4][4];
    const floatx4 zz = {0.f, 0.f, 0.f, 0.f};
    #pragma unroll
    for (int i = 0; i < 4; ++i)
        #pragma unroll
        for (int j = 0; j < 4; ++j) acc[i][j] = zz;

    for (int kt = 0; kt < 16; ++kt) {
        const int k0 = kt * 32;
        async_cp16(gA + k0, lA);
        async_cp16(gA + 64 * D + k0, lA + 4096);
        async_cp16(gB + k0, lB);
        async_cp16(gB + 64 * D + k0, lB + 4096);
        __syncthreads();
        bf16x8 af[4], bfr[4];
        #pragma unroll
        for (int i = 0; i < 4; ++i) af[i] = *(const bf16x8*)(fragA + i * 512);
        #pragma unroll
        for (int j = 0; j < 4; ++j) bfr[j] = *(const bf16x8*)(fragB + j * 512);
        #pragma unroll
        for (int i = 0; i < 4; ++i)
            #pragma unroll
            for (int j = 0; j < 4; ++j)
                acc[i][j] = __builtin_amdgcn_mfma_f32_16x16x32_bf16(af[i], bfr[j], acc[i][j], 0, 0, 0);
        __syncthreads();
    }

    float bcol[4];
    #pragma unroll
    for (int j = 0; j < 4; ++j) bcol[j] = bias[col0 + 64 * wc + 16 * j + lm];
    #pragma unroll
    for (int i = 0; i < 4; ++i) {
        #pragma unroll
        for (int r = 0; r < 4; ++r) {
            const int row = row0 + 64 * wr + 16 * i + 4 * g + r;
            float sq = 0.f;
            #pragma unroll
            for (int j = 0; j < 4; ++j) {
                const int col = col0 + 64 * wc + 16 * j + lm;
                const unsigned short h = f2bf(fast_tanh(acc[i][j][r] + bcol[j]));
                fb[(size_t)row * D + col] = h;
                const float fr = bf2f(h);
                sq += fr * fr;
            }
            #pragma unroll
            for (int d = 1; d < 16; d <<= 1) sq += __shfl_xor(sq, d);
            if (lm == 0) atomicAdd(fsq + row, sq);
        }
    }
}

// ---------------------------------------------------------------------------
// Kernel 3: fused cross-GEMM + per-lane online logsumexp (log2 domain).
// Each block: 128 rows x one 1024-col chunk (8 subtiles). Grid 64 x 8.
__global__ __launch_bounds__(256, 2)
void k_cross(const unsigned short* __restrict__ xb,
             const unsigned short* __restrict__ fb,
             const float* __restrict__ fsq,
             float* __restrict__ pmax,
             float* __restrict__ psum) {
    __shared__ unsigned short Ab[128 * 32];
    __shared__ unsigned short Bb[128 * 32];
    __shared__ float mbuf[128], sbuf[128];

    const int tid = threadIdx.x;
    const int wave = tid >> 6;
    const int lane = tid & 63;
    const int wr = wave >> 1, wc = wave & 1;
    const int g = lane >> 4;
    const int lm = lane & 15;

    const int row0 = blockIdx.x * 128;
    const int chunk = blockIdx.y;

    const int srow = tid >> 2;
    const int gsrc = (tid & 3) ^ ((srow >> 1) & 3);
    const unsigned short* gA = xb + (size_t)(row0 + srow) * D + gsrc * 8;
    char* lA = ((char*)Ab) + wave * 1024;
    char* lB = ((char*)Bb) + wave * 1024;

    const int xsel = (lm >> 1) & 3;
    const unsigned short* fragA = Ab + (64 * wr + lm) * 32 + (g ^ xsel) * 8;
    const unsigned short* fragB = Bb + (64 * wc + lm) * 32 + (g ^ xsel) * 8;

    float m_loc[4][4], s_loc[4][4];
    #pragma unroll
    for (int i = 0; i < 4; ++i)
        #pragma unroll
        for (int r = 0; r < 4; ++r) { m_loc[i][r] = -__builtin_inff(); s_loc[i][r] = 0.f; }

    for (int st = 0; st < SUBTILES; ++st) {
        const int col0 = chunk * CHUNK_COLS + st * 128;
        const unsigned short* gB = fb + (size_t)(col0 + srow) * D + gsrc * 8;

        floatx4 acc[4][4];
        const floatx4 zz = {0.f, 0.f, 0.f, 0.f};
        #pragma unroll
        for (int i = 0; i < 4; ++i)
            #pragma unroll
            for (int j = 0; j < 4; ++j) acc[i][j] = zz;

        for (int kt = 0; kt < 16; ++kt) {
            const int k0 = kt * 32;
            async_cp16(gA + k0, lA);
            async_cp16(gA + 64 * D + k0, lA + 4096);
            async_cp16(gB + k0, lB);
            async_cp16(gB + 64 * D + k0, lB + 4096);
            __syncthreads();
            bf16x8 af[4], bfr[4];
            #pragma unroll
            for (int i = 0; i < 4; ++i) af[i] = *(const bf16x8*)(fragA + i * 512);
            #pragma unroll
            for (int j = 0; j < 4; ++j) bfr[j] = *(const bf16x8*)(fragB + j * 512);
            #pragma unroll
            for (int i = 0; i < 4; ++i)
                #pragma unroll
                for (int j = 0; j < 4; ++j)
                    acc[i][j] = __builtin_amdgcn_mfma_f32_16x16x32_bf16(af[i], bfr[j], acc[i][j], 0, 0, 0);
            __syncthreads();
        }

        float hf[4];
        #pragma unroll
        for (int j = 0; j < 4; ++j)
            hf[j] = 0.5f * LOG2E * fsq[col0 + 64 * wc + 16 * j + lm];
        #pragma unroll
        for (int i = 0; i < 4; ++i) {
            #pragma unroll
            for (int r = 0; r < 4; ++r) {
                const float v0 = acc[i][0][r] - hf[0];
                const float v1 = acc[i][1][r] - hf[1];
                const float v2 = acc[i][2][r] - hf[2];
                const float v3 = acc[i][3][r] - hf[3];
                const float mm = fmaxf(fmaxf(v0, v1), fmaxf(v2, v3));
                const float nm = fmaxf(m_loc[i][r], mm);
                s_loc[i][r] = s_loc[i][r] * __builtin_exp2f(m_loc[i][r] - nm)
                            + __builtin_exp2f(v0 - nm) + __builtin_exp2f(v1 - nm)
                            + __builtin_exp2f(v2 - nm) + __builtin_exp2f(v3 - nm);
                m_loc[i][r] = nm;
            }
        }
    }

    // merge across 16-lane group
    #pragma unroll
    for (int i = 0; i < 4; ++i) {
        #pragma unroll
        for (int r = 0; r < 4; ++r) {
            float m = m_loc[i][r], s = s_loc[i][r];
            #pragma unroll
            for (int d = 1; d < 16; d <<= 1) {
                const float om = __shfl_xor(m, d);
                const float os = __shfl_xor(s, d);
                const float nm = fmaxf(m, om);
                s = s * __builtin_exp2f(m - nm) + os * __builtin_exp2f(om - nm);
                m = nm;
            }
            m_loc[i][r] = m; s_loc[i][r] = s;
        }
    }
    // merge the two column-waves via LDS, write partials
    if (wc == 0 && lm == 0) {
        #pragma unroll
        for (int i = 0; i < 4; ++i)
            #pragma unroll
            for (int r = 0; r < 4; ++r) {
                const int rl = 64 * wr + 16 * i + 4 * g + r;
                mbuf[rl] = m_loc[i][r]; sbuf[rl] = s_loc[i][r];
            }
    }
    __syncthreads();
    if (wc == 1 && lm == 0) {
        #pragma unroll
        for (int i = 0; i < 4; ++i)
            #pragma unroll
            for (int r = 0; r < 4; ++r) {
                const int rl = 64 * wr + 16 * i + 4 * g + r;
                const float om = mbuf[rl], os = sbuf[rl];
                float m = m_loc[i][r], s = s_loc[i][r];
                const float nm = fmaxf(m, om);
                s = s * __builtin_exp2f(m - nm) + os * __builtin_exp2f(om - nm);
                pmax[(size_t)(row0 + rl) * NCHUNK + chunk] = nm;
                psum[(size_t)(row0 + rl) * NCHUNK + chunk] = s;
            }
    }
}

// ---------------------------------------------------------------------------
// Kernel 4: combine partials -> out += -sum lse.
__global__ void k_finish(const float* __restrict__ pmax,
                         const float* __restrict__ psum,
                         const float* __restrict__ xsq,
                         float* __restrict__ out) {
    const int row = blockIdx.x * 256 + threadIdx.x;
    const float4* pm4 = (const float4*)(pmax + (size_t)row * NCHUNK);
    const float4* ps4 = (const float4*)(psum + (size_t)row * NCHUNK);
    float pm[NCHUNK], ps[NCHUNK];
    #pragma unroll
    for (int c = 0; c < NCHUNK / 4; ++c) {
        const float4 a = pm4[c], b = ps4[c];
        pm[4*c] = a.x; pm[4*c+1] = a.y; pm[4*c+2] = a.z; pm[4*c+3] = a.w;
        ps[4*c] = b.x; ps[4*c+1] = b.y; ps[4*c+2] = b.z; ps[4*c+3] = b.w;
    }
    float gm = -__builtin_inff();
    #pragma unroll
    for (int c = 0; c < NCHUNK; ++c) gm = fmaxf(gm, pm[c]);
    float s = 0.f;
    #pragma unroll
    for (int c = 0; c < NCHUNK; ++c) s += ps[c] * __builtin_exp2f(pm[c] - gm);
    float lse = LN2 * (gm + __builtin_log2f(s)) - 0.5f * xsq[row];
    #pragma unroll
    for (int m = 1; m < 64; m <<= 1) lse += __shfl_xor(lse, m);
    __shared__ float ws4[4];
    if ((threadIdx.x & 63) == 0) ws4[threadIdx.x >> 6] = lse;
    __syncthreads();
    if (threadIdx.x == 0) atomicAdd(out, -(ws4[0] + ws4[1] + ws4[2] + ws4[3]));
}

// ---------------------------------------------------------------------------
extern "C" void kernel_launch(void* const* d_in, const int* in_sizes, int n_in,
                              void* d_out, int out_size, void* d_ws, size_t ws_size,
                              hipStream_t stream) {
    const float* x  = (const float*)d_in[0];   // (8192, 512)
    const float* mu = (const float*)d_in[1];   // (8192, 512)
    const float* W  = (const float*)d_in[2];   // (512, 512)
    const float* b  = (const float*)d_in[3];   // (512,)

    char* ws = (char*)d_ws;
    unsigned short* xb  = (unsigned short*)(ws);                    // 8 MB
    unsigned short* fb  = (unsigned short*)(ws + (8u << 20));       // 8 MB
    unsigned short* mub = (unsigned short*)(ws + (16u << 20));      // 8 MB
    unsigned short* Wb  = (unsigned short*)(ws + (24u << 20));      // 512 KB
    float* xsq  = (float*)(ws + (25u << 20));                       // 32 KB
    float* fsq  = xsq + NROWS;                                      // 32 KB
    float* pmax = fsq + MROWS;                                      // 256 KB
    float* psum = pmax + (size_t)NROWS * NCHUNK;                    // 256 KB

    float* out = (float*)d_out;

    hipLaunchKernelGGL(k_prep, dim3(NB_X + NB_MU + NB_W), dim3(256), 0, stream,
                       x, mu, W, xb, mub, Wb, xsq, fsq, out);
    hipLaunchKernelGGL(k_fgemm, dim3(MROWS / 128, D / 128), dim3(256), 0, stream,
                       mub, Wb, b, fb, fsq);
    hipLaunchKernelGGL(k_cross, dim3(NROWS / 128, NCHUNK), dim3(256), 0, stream,
                       xb, fb, fsq, pmax, psum);
    hipLaunchKernelGGL(k_finish, dim3(NROWS / 256), dim3(256), 0, stream,
                       pmax, psum, xsq, out);
}